// Round 4
// baseline (265.044 us; speedup 1.0000x reference)
//
#include <hip/hip_runtime.h>
#include <stdint.h>

typedef unsigned short u16;
typedef unsigned int   u32;
typedef _Float16       f16;

typedef __attribute__((ext_vector_type(2))) _Float16 half2v;
typedef __attribute__((ext_vector_type(4))) _Float16 half4v;
typedef __attribute__((ext_vector_type(8))) _Float16 half8v;
typedef __attribute__((ext_vector_type(4))) float    floatx4;

#define NXS    512
#define NYS    512
#define NHEAD  8
#define DHEAD  10
#define DMODEL 80
#define DXK    768
#define DYK    283
#define DYKP   288   // padded

__device__ inline half2v pk2(float x, float y) {
  return __builtin_bit_cast(half2v, __builtin_amdgcn_cvt_pkrtz(x, y));
}
__device__ inline half4v cvt4(float4 v) {
  return __builtin_shufflevector(pk2(v.x, v.y), pk2(v.z, v.w), 0, 1, 2, 3);
}
__device__ inline half4v h4u32(u32 a, u32 b) {
  return __builtin_shufflevector(__builtin_bit_cast(half2v, a),
                                 __builtin_bit_cast(half2v, b), 0, 1, 2, 3);
}

// =====================================================================
// w_prep: transpose + fp32->f16 weights. Tq[c][k] (80x768),
// Tk/Tv[c][k] (80x288, zero-padded past k=283).
// =====================================================================
__global__ __launch_bounds__(256) void w_prep(const float* __restrict__ Wq,
                                              const float* __restrict__ Wk,
                                              const float* __restrict__ Wv,
                                              f16* __restrict__ Tq,
                                              f16* __restrict__ Tk,
                                              f16* __restrict__ Tv) {
  const int idx = blockIdx.x * 256 + threadIdx.x;
  if (idx < 80 * 768) {
    const int c = idx / 768, k = idx - c * 768;
    Tq[idx] = (f16)Wq[k * 80 + c];
  }
  if (idx < 80 * 288) {
    const int c = idx / 288, k = idx - c * 288;
    float a = 0.f, b = 0.f;
    if (k < DYK) { a = Wk[k * 80 + c]; b = Wv[k * 80 + c]; }
    Tk[idx] = (f16)a;
    Tv[idx] = (f16)b;
  }
}

// =====================================================================
// proj (merged, NO LDS / NO barriers): MFMA fragments loaded directly
// from global. A-frag = 8 consecutive fp32 of X/Y row (m=lane&15,
// k=quad*8+j); B-frag = 8 consecutive f16 of transposed-W row (L2-hit).
// blocks 0..511: Q path (64 rows each); 512..1023: KV path.
// =====================================================================
__global__ __launch_bounds__(256) void proj(const float* __restrict__ X,
                                            const float* __restrict__ Y,
                                            const f16* __restrict__ Wtq,
                                            const f16* __restrict__ Wtk,
                                            const f16* __restrict__ Wtv,
                                            f16* __restrict__ Qw,
                                            f16* __restrict__ Kw,
                                            f16* __restrict__ Vw) {
  const int t = threadIdx.x;
  const int wv = t >> 6, lane = t & 63, m16 = lane & 15, quad = lane >> 4;
  const int blk = blockIdx.x;

  if (blk < 512) {
    // ---------------- Q path ----------------
    const int rowb = blk * 64 + wv * 16;
    const float* xr = X + (size_t)(rowb + m16) * DXK + quad * 8;
    const f16* wb = Wtq + (size_t)m16 * DXK + quad * 8;

    floatx4 acc[5];
#pragma unroll
    for (int i = 0; i < 5; ++i) acc[i] = (floatx4){0.f, 0.f, 0.f, 0.f};

#pragma unroll 4
    for (int s = 0; s < 24; ++s) {
      const int k0 = s * 32;
      const float4 x0 = *(const float4*)(xr + k0);
      const float4 x1 = *(const float4*)(xr + k0 + 4);
      const half8v a = __builtin_shufflevector(cvt4(x0), cvt4(x1),
                                               0, 1, 2, 3, 4, 5, 6, 7);
#pragma unroll
      for (int nt = 0; nt < 5; ++nt) {
        const half8v b = *(const half8v*)(wb + (size_t)nt * 16 * DXK + k0);
        acc[nt] = __builtin_amdgcn_mfma_f32_16x16x32_f16(a, b, acc[nt], 0, 0, 0);
      }
    }
#pragma unroll
    for (int nt = 0; nt < 5; ++nt) {
      const int col = nt * 16 + m16;
#pragma unroll
      for (int p = 0; p < 4; ++p)
        Qw[(size_t)(rowb + quad * 4 + p) * DMODEL + col] = (f16)acc[nt][p];
    }
  } else {
    // ---------------- KV path ----------------
    const int rowb = (blk - 512) * 64 + wv * 16;
    const float* yr = Y + (size_t)(rowb + m16) * DYK + quad * 8;
    const f16* wbk = Wtk + (size_t)m16 * DYKP + quad * 8;
    const f16* wbv = Wtv + (size_t)m16 * DYKP + quad * 8;

    floatx4 ak[5], av[5];
#pragma unroll
    for (int i = 0; i < 5; ++i) {
      ak[i] = (floatx4){0.f, 0.f, 0.f, 0.f};
      av[i] = (floatx4){0.f, 0.f, 0.f, 0.f};
    }

#pragma unroll 2
    for (int s = 0; s < 9; ++s) {
      const int k0 = s * 32;
      float y8[8];
      if (s < 8) {
#pragma unroll
        for (int j = 0; j < 8; ++j) y8[j] = yr[k0 + j];
      } else {
#pragma unroll
        for (int j = 0; j < 8; ++j) {
          const int k = k0 + quad * 8 + j;
          y8[j] = (k < DYK) ? yr[k0 + j] : 0.f;
        }
      }
      const half8v a = __builtin_shufflevector(
          cvt4((float4){y8[0], y8[1], y8[2], y8[3]}),
          cvt4((float4){y8[4], y8[5], y8[6], y8[7]}), 0, 1, 2, 3, 4, 5, 6, 7);
#pragma unroll
      for (int nt = 0; nt < 5; ++nt) {
        const half8v bk = *(const half8v*)(wbk + (size_t)nt * 16 * DYKP + k0);
        ak[nt] = __builtin_amdgcn_mfma_f32_16x16x32_f16(a, bk, ak[nt], 0, 0, 0);
        const half8v bv = *(const half8v*)(wbv + (size_t)nt * 16 * DYKP + k0);
        av[nt] = __builtin_amdgcn_mfma_f32_16x16x32_f16(a, bv, av[nt], 0, 0, 0);
      }
    }
#pragma unroll
    for (int nt = 0; nt < 5; ++nt) {
      const int col = nt * 16 + m16;
      const int h = col / 10, d = col - h * 10;
#pragma unroll
      for (int p = 0; p < 4; ++p) {
        const int grow = rowb + quad * 4 + p;
        const int bb = grow >> 9, ny = grow & 511;
        const size_t o = (((size_t)bb * NHEAD + h) * NYS + ny) * DHEAD + d;
        Kw[o] = (f16)ak[nt][p];
        Vw[o] = (f16)av[nt][p];
      }
    }
  }
}

// =====================================================================
// attn: 2 blocks per (b,h) (grid 1024), 4 waves, 4 q-tiles/wave.
// K,V^T in LDS (odd-dword strides 22 / 522 -> <=2-way bank aliasing);
// Q fragments + residual direct from global. Dual accumulators break
// the oacc MFMA dependency chain. No-max softmax, q pre-scaled.
// =====================================================================
__global__ __launch_bounds__(256) void attn(const f16* __restrict__ Q,
                                            const f16* __restrict__ K,
                                            const f16* __restrict__ V,
                                            float* __restrict__ O) {
  __shared__ f16 Ks[512 * 22];   // [key][d], d 10..15 zeroed
  __shared__ f16 Vt[16 * 522];   // [d][key], d rows 10..15 zeroed
  const int t = threadIdx.x;
  const int wv = t >> 6, lane = t & 63, m16 = lane & 15, quad = lane >> 4;
  const int bh = blockIdx.x >> 1, half = blockIdx.x & 1;
  const int b = bh >> 3, h = bh & 7;

  const u32* Kg = (const u32*)K + (size_t)bh * NYS * 5;
  const u32* Vg = (const u32*)V + (size_t)bh * NYS * 5;
  for (int idx = t; idx < 2560; idx += 256) {
    const u32 row = (u32)idx / 5u, c = (u32)idx - row * 5u;
    const half2v kv = __builtin_bit_cast(half2v, Kg[idx]);
    Ks[row * 22 + 2 * c]     = kv[0];
    Ks[row * 22 + 2 * c + 1] = kv[1];
    const half2v vv = __builtin_bit_cast(half2v, Vg[idx]);
    Vt[(2 * c) * 522 + row]     = vv[0];
    Vt[(2 * c + 1) * 522 + row] = vv[1];
  }
  for (int idx = t; idx < 3072; idx += 256) {  // Ks d-pad 10..15
    const u32 row = (u32)idx / 6u, d = 10u + ((u32)idx - row * 6u);
    Ks[row * 22 + d] = (f16)0.f;
  }
  for (int idx = t; idx < 6 * 522; idx += 256)  // Vt rows 10..15
    Vt[10 * 522 + idx] = (f16)0.f;
  __syncthreads();

  const float scale = 0.31622776601683794f;  // 1/sqrt(10)
#pragma unroll 1
  for (int i = 0; i < 4; ++i) {
    const int qt = half * 16 + wv * 4 + i;
    const int qrow = qt * 16 + m16;
    const u32* Qg32 = (const u32*)(Q + ((size_t)b * NXS + qrow) * DMODEL + h * DHEAD);
    float s0 = 0.f, s1 = 0.f, s2 = 0.f, s3 = 0.f;
    if (quad < 2) {
      const u32 ua = Qg32[quad * 2], ub = Qg32[quad * 2 + 1];
      const half2v ha = __builtin_bit_cast(half2v, ua);
      const half2v hb = __builtin_bit_cast(half2v, ub);
      s0 = (float)ha[0]; s1 = (float)ha[1]; s2 = (float)hb[0]; s3 = (float)hb[1];
    } else if (quad == 2) {
      const u32 ua = Qg32[4];
      const half2v ha = __builtin_bit_cast(half2v, ua);
      s0 = (float)ha[0]; s1 = (float)ha[1];
    }
    const half4v qf = __builtin_shufflevector(pk2(s0 * scale, s1 * scale),
                                              pk2(s2 * scale, s3 * scale),
                                              0, 1, 2, 3);
    floatx4 o0 = (floatx4){0.f, 0.f, 0.f, 0.f};
    floatx4 o1 = (floatx4){0.f, 0.f, 0.f, 0.f};
    float l0 = 0.f, l1 = 0.f;
    for (int kt = 0; kt < 32; kt += 2) {
#pragma unroll
      for (int u = 0; u < 2; ++u) {
        const int ktu = kt + u;
        const int kb = (ktu * 16 + m16) * 22 + quad * 4;
        const half4v kf = h4u32(*(const u32*)&Ks[kb], *(const u32*)&Ks[kb + 2]);
        const floatx4 s = __builtin_amdgcn_mfma_f32_16x16x16f16(
            kf, qf, (floatx4){0.f, 0.f, 0.f, 0.f}, 0, 0, 0);
        const float p0 = __expf(s[0]);
        const float p1 = __expf(s[1]);
        const float p2 = __expf(s[2]);
        const float p3 = __expf(s[3]);
        const half4v pf = __builtin_shufflevector(pk2(p0, p1), pk2(p2, p3),
                                                  0, 1, 2, 3);
        const int vb = m16 * 522 + ktu * 16 + quad * 4;
        const half4v vf = h4u32(*(const u32*)&Vt[vb], *(const u32*)&Vt[vb + 2]);
        if (u == 0) {
          l0 += (p0 + p1) + (p2 + p3);
          o0 = __builtin_amdgcn_mfma_f32_16x16x16f16(pf, vf, o0, 0, 0, 0);
        } else {
          l1 += (p0 + p1) + (p2 + p3);
          o1 = __builtin_amdgcn_mfma_f32_16x16x16f16(pf, vf, o1, 0, 0, 0);
        }
      }
    }
    float lp = l0 + l1;
    lp += __shfl_xor(lp, 16);
    lp += __shfl_xor(lp, 32);
#pragma unroll
    for (int p = 0; p < 4; ++p) {
      const int rq = qt * 16 + quad * 4 + p;
      const float lr = __shfl(lp, quad * 4 + p);
      if (m16 < DHEAD) {
        const float qres = (float)Q[((size_t)b * NXS + rq) * DMODEL + h * DHEAD + m16];
        O[((size_t)b * NXS + rq) * DMODEL + h * DHEAD + m16] =
            qres + (o0[p] + o1[p]) / lr;
      }
    }
  }
}

extern "C" void kernel_launch(void* const* d_in, const int* in_sizes, int n_in,
                              void* d_out, int out_size, void* d_ws, size_t ws_size,
                              hipStream_t stream) {
  const float* x  = (const float*)d_in[0];
  const float* y  = (const float*)d_in[1];
  const float* Wq = (const float*)d_in[2];
  const float* Wk = (const float*)d_in[3];
  const float* Wv = (const float*)d_in[4];
  float* out = (float*)d_out;

  char* ws = (char*)d_ws;
  f16* Wtq = (f16*)(ws);                  // 80*768*2  = 122880 B
  f16* Wtk = (f16*)(ws + 122880);         // 80*288*2  =  46080 B
  f16* Wtv = (f16*)(ws + 168960);         // 46080 B
  f16* Qw  = (f16*)(ws + 262144);         // 5242880 B
  f16* Kw  = (f16*)(ws + 5505024);
  f16* Vw  = (f16*)(ws + 10747904);

  w_prep<<<240, 256, 0, stream>>>(Wq, Wk, Wv, Wtq, Wtk, Wtv);
  proj  <<<1024, 256, 0, stream>>>(x, y, Wtq, Wtk, Wtv, Qw, Kw, Vw);
  attn  <<<1024, 256, 0, stream>>>(Qw, Kw, Vw, out);
}

// Round 5
// 236.974 us; speedup vs baseline: 1.1184x; 1.1184x over previous
//
#include <hip/hip_runtime.h>
#include <stdint.h>

typedef unsigned short u16;
typedef unsigned int   u32;
typedef _Float16       f16;

typedef __attribute__((ext_vector_type(2))) _Float16 half2v;
typedef __attribute__((ext_vector_type(4))) _Float16 half4v;
typedef __attribute__((ext_vector_type(8))) _Float16 half8v;
typedef __attribute__((ext_vector_type(4))) float    floatx4;

#define NXS    512
#define NYS    512
#define NHEAD  8
#define DHEAD  10
#define DMODEL 80
#define DXK    768
#define DYK    283
#define DYKP   288   // padded

__device__ inline half2v pk2(float x, float y) {
  return __builtin_bit_cast(half2v, __builtin_amdgcn_cvt_pkrtz(x, y));
}
__device__ inline half4v cvt4(float4 v) {
  return __builtin_shufflevector(pk2(v.x, v.y), pk2(v.z, v.w), 0, 1, 2, 3);
}
__device__ inline half4v h4u32(u32 a, u32 b) {
  return __builtin_shufflevector(__builtin_bit_cast(half2v, a),
                                 __builtin_bit_cast(half2v, b), 0, 1, 2, 3);
}

// =====================================================================
// w_prep: transpose + fp32->f16 weights. Tq[c][k] (80x768),
// Tk/Tv[c][k] (80x288, zero-padded past k=283).
// =====================================================================
__global__ __launch_bounds__(256) void w_prep(const float* __restrict__ Wq,
                                              const float* __restrict__ Wk,
                                              const float* __restrict__ Wv,
                                              f16* __restrict__ Tq,
                                              f16* __restrict__ Tk,
                                              f16* __restrict__ Tv) {
  const int idx = blockIdx.x * 256 + threadIdx.x;
  if (idx < 80 * 768) {
    const int c = idx / 768, k = idx - c * 768;
    Tq[idx] = (f16)Wq[k * 80 + c];
  }
  if (idx < 80 * 288) {
    const int c = idx / 288, k = idx - c * 288;
    float a = 0.f, b = 0.f;
    if (k < DYK) { a = Wk[k * 80 + c]; b = Wv[k * 80 + c]; }
    Tk[idx] = (f16)a;
    Tv[idx] = (f16)b;
  }
}

// =====================================================================
// proj (merged): LDS-staged, register-prefetch pipelined, COALESCED
// global loads only (X via float4 16B/lane; Y via dword with lane->k
// mapping; W via uint4 from pre-transposed f16). blocks 0..511 = Q path
// (64 rows, 24 K-steps); 512..1023 = KV path (64 rows, 9 K-steps).
// LDS tiles stride 40 f16 (80 B = 20 banks -> 2-way aliasing, free).
// =====================================================================
__global__ __launch_bounds__(256) void proj(const float* __restrict__ X,
                                            const float* __restrict__ Y,
                                            const f16* __restrict__ Wtq,
                                            const f16* __restrict__ Wtk,
                                            const f16* __restrict__ Wtv,
                                            f16* __restrict__ Qw,
                                            f16* __restrict__ Kw,
                                            f16* __restrict__ Vw) {
  const int t = threadIdx.x;
  const int wv = t >> 6, lane = t & 63, m16 = lane & 15, quad = lane >> 4;
  const int blk = blockIdx.x;

  if (blk < 512) {
    // ---------------- Q path ----------------
    __shared__ f16 Xs[64 * 40];
    __shared__ f16 Ws[80 * 40];
    const int row0 = blk * 64;
    const int xr_r = t >> 3, xr_k = (t & 7) << 2;   // rows 0..31, +32 pair
    const int wi0 = t, wi1 = t + 160;

    float4 xr0, xr1;
    uint4 wr0, wr1;
    xr0 = *(const float4*)&X[(size_t)(row0 + xr_r) * DXK + xr_k];
    xr1 = *(const float4*)&X[(size_t)(row0 + xr_r + 32) * DXK + xr_k];
    if (t < 160) {
      wr0 = *(const uint4*)&Wtq[(wi0 >> 2) * DXK + (wi0 & 3) * 8];
      wr1 = *(const uint4*)&Wtq[(wi1 >> 2) * DXK + (wi1 & 3) * 8];
    }

    floatx4 acc[5];
#pragma unroll
    for (int i = 0; i < 5; ++i) acc[i] = (floatx4){0.f, 0.f, 0.f, 0.f};

    for (int s = 0; s < 24; ++s) {
      if (s) __syncthreads();
      *(half4v*)&Xs[xr_r * 40 + xr_k] = cvt4(xr0);
      *(half4v*)&Xs[(xr_r + 32) * 40 + xr_k] = cvt4(xr1);
      if (t < 160) {
        *(uint4*)&Ws[(wi0 >> 2) * 40 + (wi0 & 3) * 8] = wr0;
        *(uint4*)&Ws[(wi1 >> 2) * 40 + (wi1 & 3) * 8] = wr1;
      }
      __syncthreads();
      if (s < 23) {
        const int k0 = (s + 1) * 32;
        xr0 = *(const float4*)&X[(size_t)(row0 + xr_r) * DXK + k0 + xr_k];
        xr1 = *(const float4*)&X[(size_t)(row0 + xr_r + 32) * DXK + k0 + xr_k];
        if (t < 160) {
          wr0 = *(const uint4*)&Wtq[(wi0 >> 2) * DXK + k0 + (wi0 & 3) * 8];
          wr1 = *(const uint4*)&Wtq[(wi1 >> 2) * DXK + k0 + (wi1 & 3) * 8];
        }
      }
      const half8v a = *(const half8v*)&Xs[(wv * 16 + m16) * 40 + quad * 8];
#pragma unroll
      for (int nt = 0; nt < 5; ++nt) {
        const half8v b = *(const half8v*)&Ws[(nt * 16 + m16) * 40 + quad * 8];
        acc[nt] = __builtin_amdgcn_mfma_f32_16x16x32_f16(a, b, acc[nt], 0, 0, 0);
      }
    }
#pragma unroll
    for (int nt = 0; nt < 5; ++nt) {
      const int col = nt * 16 + m16;
#pragma unroll
      for (int p = 0; p < 4; ++p) {
        const int grow = row0 + wv * 16 + quad * 4 + p;
        Qw[(size_t)grow * DMODEL + col] = (f16)acc[nt][p];
      }
    }
  } else {
    // ---------------- KV path ----------------
    __shared__ f16 Ys[64 * 40];
    __shared__ f16 Wks[80 * 40];
    __shared__ f16 Wvs[80 * 40];
    const int row0 = (blk - 512) * 64;
    const int wi0 = t, wi1 = t + 160;

    float yr[8];
    uint4 wk0, wk1, wv0, wv1;
#pragma unroll
    for (int i = 0; i < 8; ++i) {
      const int idx = t + 256 * i;                  // consecutive t -> consecutive k
      const int r = idx >> 5, kk = idx & 31;
      yr[i] = Y[(size_t)(row0 + r) * DYK + kk];
    }
    if (t < 160) {
      wk0 = *(const uint4*)&Wtk[(wi0 >> 2) * DYKP + (wi0 & 3) * 8];
      wk1 = *(const uint4*)&Wtk[(wi1 >> 2) * DYKP + (wi1 & 3) * 8];
      wv0 = *(const uint4*)&Wtv[(wi0 >> 2) * DYKP + (wi0 & 3) * 8];
      wv1 = *(const uint4*)&Wtv[(wi1 >> 2) * DYKP + (wi1 & 3) * 8];
    }

    floatx4 ak[5], av[5];
#pragma unroll
    for (int i = 0; i < 5; ++i) {
      ak[i] = (floatx4){0.f, 0.f, 0.f, 0.f};
      av[i] = (floatx4){0.f, 0.f, 0.f, 0.f};
    }

    for (int s = 0; s < 9; ++s) {   // 288/32
      if (s) __syncthreads();
#pragma unroll
      for (int i = 0; i < 8; ++i) {
        const int idx = t + 256 * i;
        Ys[(idx >> 5) * 40 + (idx & 31)] = (f16)yr[i];
      }
      if (t < 160) {
        *(uint4*)&Wks[(wi0 >> 2) * 40 + (wi0 & 3) * 8] = wk0;
        *(uint4*)&Wks[(wi1 >> 2) * 40 + (wi1 & 3) * 8] = wk1;
        *(uint4*)&Wvs[(wi0 >> 2) * 40 + (wi0 & 3) * 8] = wv0;
        *(uint4*)&Wvs[(wi1 >> 2) * 40 + (wi1 & 3) * 8] = wv1;
      }
      __syncthreads();
      if (s < 8) {
        const int k0 = (s + 1) * 32;
#pragma unroll
        for (int i = 0; i < 8; ++i) {
          const int idx = t + 256 * i;
          const int r = idx >> 5, k = k0 + (idx & 31);
          yr[i] = (k < DYK) ? Y[(size_t)(row0 + r) * DYK + k] : 0.f;
        }
        if (t < 160) {
          wk0 = *(const uint4*)&Wtk[(wi0 >> 2) * DYKP + k0 + (wi0 & 3) * 8];
          wk1 = *(const uint4*)&Wtk[(wi1 >> 2) * DYKP + k0 + (wi1 & 3) * 8];
          wv0 = *(const uint4*)&Wtv[(wi0 >> 2) * DYKP + k0 + (wi0 & 3) * 8];
          wv1 = *(const uint4*)&Wtv[(wi1 >> 2) * DYKP + k0 + (wi1 & 3) * 8];
        }
      }
      const half8v a = *(const half8v*)&Ys[(wv * 16 + m16) * 40 + quad * 8];
#pragma unroll
      for (int nt = 0; nt < 5; ++nt) {
        const half8v bk = *(const half8v*)&Wks[(nt * 16 + m16) * 40 + quad * 8];
        ak[nt] = __builtin_amdgcn_mfma_f32_16x16x32_f16(a, bk, ak[nt], 0, 0, 0);
        const half8v bv = *(const half8v*)&Wvs[(nt * 16 + m16) * 40 + quad * 8];
        av[nt] = __builtin_amdgcn_mfma_f32_16x16x32_f16(a, bv, av[nt], 0, 0, 0);
      }
    }
#pragma unroll
    for (int nt = 0; nt < 5; ++nt) {
      const int col = nt * 16 + m16;
      const int h = col / 10, d = col - h * 10;
#pragma unroll
      for (int p = 0; p < 4; ++p) {
        const int grow = row0 + wv * 16 + quad * 4 + p;
        const int bb = grow >> 9, ny = grow & 511;
        const size_t o = (((size_t)bb * NHEAD + h) * NYS + ny) * DHEAD + d;
        Kw[o] = (f16)ak[nt][p];
        Vw[o] = (f16)av[nt][p];
      }
    }
  }
}

// =====================================================================
// attn: 2 blocks per (b,h) (grid 1024), 4 waves, 4 q-tiles/wave.
// K,V^T in LDS (odd-dword strides 22 / 522 -> <=2-way bank aliasing);
// Q fragments + residual direct from global. Dual accumulators break
// the oacc MFMA dependency chain. No-max softmax, q pre-scaled.
// =====================================================================
__global__ __launch_bounds__(256) void attn(const f16* __restrict__ Q,
                                            const f16* __restrict__ K,
                                            const f16* __restrict__ V,
                                            float* __restrict__ O) {
  __shared__ f16 Ks[512 * 22];   // [key][d], d 10..15 zeroed
  __shared__ f16 Vt[16 * 522];   // [d][key], d rows 10..15 zeroed
  const int t = threadIdx.x;
  const int wv = t >> 6, lane = t & 63, m16 = lane & 15, quad = lane >> 4;
  const int bh = blockIdx.x >> 1, half = blockIdx.x & 1;
  const int b = bh >> 3, h = bh & 7;

  const u32* Kg = (const u32*)K + (size_t)bh * NYS * 5;
  const u32* Vg = (const u32*)V + (size_t)bh * NYS * 5;
  for (int idx = t; idx < 2560; idx += 256) {
    const u32 row = (u32)idx / 5u, c = (u32)idx - row * 5u;
    const half2v kv = __builtin_bit_cast(half2v, Kg[idx]);
    Ks[row * 22 + 2 * c]     = kv[0];
    Ks[row * 22 + 2 * c + 1] = kv[1];
    const half2v vvv = __builtin_bit_cast(half2v, Vg[idx]);
    Vt[(2 * c) * 522 + row]     = vvv[0];
    Vt[(2 * c + 1) * 522 + row] = vvv[1];
  }
  for (int idx = t; idx < 3072; idx += 256) {  // Ks d-pad 10..15
    const u32 row = (u32)idx / 6u, d = 10u + ((u32)idx - row * 6u);
    Ks[row * 22 + d] = (f16)0.f;
  }
  for (int idx = t; idx < 6 * 522; idx += 256)  // Vt rows 10..15
    Vt[10 * 522 + idx] = (f16)0.f;
  __syncthreads();

  const float scale = 0.31622776601683794f;  // 1/sqrt(10)
#pragma unroll 1
  for (int i = 0; i < 4; ++i) {
    const int qt = half * 16 + wv * 4 + i;
    const int qrow = qt * 16 + m16;
    const u32* Qg32 = (const u32*)(Q + ((size_t)b * NXS + qrow) * DMODEL + h * DHEAD);
    float s0 = 0.f, s1 = 0.f, s2 = 0.f, s3 = 0.f;
    if (quad < 2) {
      const u32 ua = Qg32[quad * 2], ub = Qg32[quad * 2 + 1];
      const half2v ha = __builtin_bit_cast(half2v, ua);
      const half2v hb = __builtin_bit_cast(half2v, ub);
      s0 = (float)ha[0]; s1 = (float)ha[1]; s2 = (float)hb[0]; s3 = (float)hb[1];
    } else if (quad == 2) {
      const u32 ua = Qg32[4];
      const half2v ha = __builtin_bit_cast(half2v, ua);
      s0 = (float)ha[0]; s1 = (float)ha[1];
    }
    const half4v qf = __builtin_shufflevector(pk2(s0 * scale, s1 * scale),
                                              pk2(s2 * scale, s3 * scale),
                                              0, 1, 2, 3);
    floatx4 o0 = (floatx4){0.f, 0.f, 0.f, 0.f};
    floatx4 o1 = (floatx4){0.f, 0.f, 0.f, 0.f};
    float l0 = 0.f, l1 = 0.f;
    for (int kt = 0; kt < 32; kt += 2) {
#pragma unroll
      for (int u = 0; u < 2; ++u) {
        const int ktu = kt + u;
        const int kb = (ktu * 16 + m16) * 22 + quad * 4;
        const half4v kf = h4u32(*(const u32*)&Ks[kb], *(const u32*)&Ks[kb + 2]);
        const floatx4 s = __builtin_amdgcn_mfma_f32_16x16x16f16(
            kf, qf, (floatx4){0.f, 0.f, 0.f, 0.f}, 0, 0, 0);
        const float p0 = __expf(s[0]);
        const float p1 = __expf(s[1]);
        const float p2 = __expf(s[2]);
        const float p3 = __expf(s[3]);
        const half4v pf = __builtin_shufflevector(pk2(p0, p1), pk2(p2, p3),
                                                  0, 1, 2, 3);
        const int vb = m16 * 522 + ktu * 16 + quad * 4;
        const half4v vf = h4u32(*(const u32*)&Vt[vb], *(const u32*)&Vt[vb + 2]);
        if (u == 0) {
          l0 += (p0 + p1) + (p2 + p3);
          o0 = __builtin_amdgcn_mfma_f32_16x16x16f16(pf, vf, o0, 0, 0, 0);
        } else {
          l1 += (p0 + p1) + (p2 + p3);
          o1 = __builtin_amdgcn_mfma_f32_16x16x16f16(pf, vf, o1, 0, 0, 0);
        }
      }
    }
    float lp = l0 + l1;
    lp += __shfl_xor(lp, 16);
    lp += __shfl_xor(lp, 32);
#pragma unroll
    for (int p = 0; p < 4; ++p) {
      const int rq = qt * 16 + quad * 4 + p;
      const float lr = __shfl(lp, quad * 4 + p);
      if (m16 < DHEAD) {
        const float qres = (float)Q[((size_t)b * NXS + rq) * DMODEL + h * DHEAD + m16];
        O[((size_t)b * NXS + rq) * DMODEL + h * DHEAD + m16] =
            qres + (o0[p] + o1[p]) / lr;
      }
    }
  }
}

extern "C" void kernel_launch(void* const* d_in, const int* in_sizes, int n_in,
                              void* d_out, int out_size, void* d_ws, size_t ws_size,
                              hipStream_t stream) {
  const float* x  = (const float*)d_in[0];
  const float* y  = (const float*)d_in[1];
  const float* Wq = (const float*)d_in[2];
  const float* Wk = (const float*)d_in[3];
  const float* Wv = (const float*)d_in[4];
  float* out = (float*)d_out;

  char* ws = (char*)d_ws;
  f16* Wtq = (f16*)(ws);                  // 80*768*2  = 122880 B
  f16* Wtk = (f16*)(ws + 122880);         // 80*288*2  =  46080 B
  f16* Wtv = (f16*)(ws + 168960);         // 46080 B
  f16* Qw  = (f16*)(ws + 262144);         // 5242880 B
  f16* Kw  = (f16*)(ws + 5505024);
  f16* Vw  = (f16*)(ws + 10747904);

  w_prep<<<240, 256, 0, stream>>>(Wq, Wk, Wv, Wtq, Wtk, Wtv);
  proj  <<<1024, 256, 0, stream>>>(x, y, Wtq, Wtk, Wtv, Qw, Kw, Vw);
  attn  <<<1024, 256, 0, stream>>>(Qw, Kw, Vw, out);
}